// Round 10
// baseline (89.656 us; speedup 1.0000x reference)
//
#include <hip/hip_runtime.h>
#include <math.h>

#define NPIX   4096
#define FDIM   64
#define BATCH  2
#define SPLIT  32
#define CHUNK  (NPIX / SPLIT)      // 128
#define NTILE  (CHUNK / 16)        // 8 m-tiles of 16
#define BLKN   256                 // n-rows per block (4 waves x 4 groups x 16)
#define PITCH  72                  // shorts per LDS X row (64 + 8 pad)

typedef __attribute__((ext_vector_type(8))) short short8;
typedef __attribute__((ext_vector_type(4))) float floatx4;

__device__ __forceinline__ float exp2f_(float x) { return __builtin_amdgcn_exp2f(x); }

// round-to-nearest-even fp32 -> bf16
__device__ __forceinline__ short f2bf(float x) {
    union { float f; unsigned u; } c; c.f = x;
    unsigned r = (c.u + 0x7FFFu + ((c.u >> 16) & 1u)) >> 16;
    return (short)r;
}

// ---------------- LAB helpers ----------------
__device__ __forceinline__ float gamma_expand(float u) {
    return u > 0.04045f ? powf((u + 0.055f) * (1.0f / 1.055f), 2.4f)
                        : u * (1.0f / 12.92f);
}
__device__ __forceinline__ float lab_f(float t) {
    return t > 0.008856f ? cbrtf(t) : 7.787f * t + (16.0f / 116.0f);
}

// ---------------- Kernel 1: prep = feat transpose->bf16 (blocks 0..255) + LAB (blocks 256..319) ----
// f0t/f1t: [b][n][f] bf16; f0t pre-scaled by log2(e)/0.07 (logits in log2 space).
__global__ __launch_bounds__(256) void prep_kernel(
    const float* __restrict__ rgb0, const float* __restrict__ rgb1,
    const float* __restrict__ feat0, const float* __restrict__ feat1,
    float* __restrict__ lab0, float* __restrict__ lab1,
    short* __restrict__ f0t, short* __restrict__ f1t,
    float* __restrict__ out)
{
    int bid = blockIdx.x;
    int tid = threadIdx.x;

    if (bid < 256) {
        __shared__ short Tsm[64 * 72];
        int pair = bid >> 6;            // 0..3
        int tensor = pair >> 1;         // 0: f0, 1: f1
        int bb = pair & 1;
        int n0 = (bid & 63) * 64;
        const float* src = (tensor ? feat1 : feat0) + (size_t)bb * FDIM * NPIX;
        short* dst = (tensor ? f1t : f0t) + (size_t)bb * NPIX * FDIM;
        float scale = tensor ? 1.0f : (1.442695040888963f / 0.07f);

        int f = tid >> 2;
        int slot = tid & 3;
        #pragma unroll
        for (int i = 0; i < 4; ++i) {
            int col4 = slot * 4 + i;
            int noff = col4 * 4;
            float4 v = *(const float4*)&src[(size_t)f * NPIX + n0 + noff];
            Tsm[(noff + 0) * 72 + f] = f2bf(v.x * scale);
            Tsm[(noff + 1) * 72 + f] = f2bf(v.y * scale);
            Tsm[(noff + 2) * 72 + f] = f2bf(v.z * scale);
            Tsm[(noff + 3) * 72 + f] = f2bf(v.w * scale);
        }
        __syncthreads();
        #pragma unroll
        for (int i = 0; i < 2; ++i) {
            int idx = i * 256 + tid;
            int row = idx >> 3, ch = idx & 7;
            *(short8*)&dst[(size_t)(n0 + row) * FDIM + ch * 8] =
                *(const short8*)&Tsm[row * 72 + ch * 8];
        }
        return;
    }

    if (bid == 256 && tid == 0) out[0] = 0.0f;   // zero-init for loss atomicAdd

    // LAB branch
    int gid = (bid - 256) * 256 + tid;     // 0 .. 16383
    int img = gid / (BATCH * NPIX);
    int rem = gid - img * (BATCH * NPIX);
    int b = rem / NPIX;
    int n = rem - b * NPIX;
    const float* rgb = img ? rgb1 : rgb0;
    float* lab = img ? lab1 : lab0;

    size_t i0 = (size_t)(b * 3 + 0) * NPIX + n;
    size_t i1 = (size_t)(b * 3 + 1) * NPIX + n;
    size_t i2 = (size_t)(b * 3 + 2) * NPIX + n;

    float r = gamma_expand(rgb[i0] + 0.5f);
    float g = gamma_expand(rgb[i1] + 0.5f);
    float bl = gamma_expand(rgb[i2] + 0.5f);

    float X = (0.412453f * r + 0.357580f * g + 0.180423f * bl) * (1.0f / 0.95047f);
    float Y = (0.212671f * r + 0.715160f * g + 0.072169f * bl);
    float Z = (0.019334f * r + 0.119193f * g + 0.950227f * bl) * (1.0f / 1.08883f);

    float fx = lab_f(X), fy = lab_f(Y), fz = lab_f(Z);
    float L = 116.0f * fy - 16.0f;
    float a = 500.0f * (fx - fy);
    float bb2 = 200.0f * (fy - fz);

    lab[i0] = (L - 50.0f) * (1.0f / 100.0f);
    lab[i1] = a * (1.0f / 110.0f);
    lab[i2] = bb2 * (1.0f / 110.0f);
}

// ---------------- Kernel 2: MFMA attn — LDS-shared X + 4 n-groups/wave ----------------
// mfma(X=f1 rows m, Y=f0 rows n): D[row=q*4+r <-> m][col=lane&15 <-> n]  (bench-verified R5-R9).
// 256-thread blocks, grid 1024 -> 4 blocks/CU (LDS 21 KB), 16 waves/CU. X chunk (128 rows)
// staged once per block in LDS, shared by all 4 waves; each wave covers 64 n-rows (4 groups),
// so each ds_read pair feeds 8 MFMA. One barrier total; main loop has zero global loads.
__global__ __launch_bounds__(256, 4) void attn_kernel(
    const short* __restrict__ f0t, const short* __restrict__ f1t,
    const float* __restrict__ lab1ws, float* __restrict__ partials)
{
    __shared__ short Xs[CHUNK * PITCH];    // 18 KB
    __shared__ float Lt[3 * CHUNK];        // 1.5 KB

    int bid = blockIdx.x;
    int rowblk = bid & 15;                 // 16 rowblocks of 256 n
    int chunk = (bid >> 4) & (SPLIT - 1);
    int b = bid >> 9;
    int tid = threadIdx.x;
    int wv = tid >> 6;                     // 0..3
    int l = tid & 63;
    int c = l & 15;
    int q = l >> 4;

    int n_base = rowblk * BLKN + wv * 64;  // this wave: 4 groups of 16 rows
    int m_base = chunk * CHUNK;

    // stage labels for the m-chunk (3 x 128 floats)
    if (tid < 96) {
        int cc = tid >> 5;
        int m4 = tid & 31;
        *(float4*)&Lt[cc * CHUNK + m4 * 4] =
            *(const float4*)&lab1ws[(size_t)(b * 3 + cc) * NPIX + m_base + m4 * 4];
    }

    // stage X: 128 rows x 64 bf16 = 1024 chunks of 16B; straight copy, padded rows
    {
        const short8* src = (const short8*)(f1t + ((size_t)b * NPIX + m_base) * FDIM);
        #pragma unroll
        for (int i = 0; i < 4; ++i) {
            int g = i * 256 + tid;         // 0..1023
            int m = g >> 3, kc = g & 7;
            *(short8*)&Xs[m * PITCH + kc * 8] = src[g];
        }
    }

    // Y fragments (f0, n-rows), 4 groups, straight from global (one-time)
    short8 ya[4], yb[4];
    #pragma unroll
    for (int g = 0; g < 4; ++g) {
        const short8* yp = (const short8*)(f0t +
            ((size_t)b * NPIX + n_base + g * 16 + c) * FDIM + q * 8);
        ya[g] = yp[0];
        yb[g] = yp[4];
    }

    __syncthreads();

    float ms[4], sum[4], aA[4], aB[4], aC[4];
    #pragma unroll
    for (int g = 0; g < 4; ++g) {
        ms[g] = -INFINITY; sum[g] = 0.0f;
        aA[g] = 0.0f; aB[g] = 0.0f; aC[g] = 0.0f;
    }

    #pragma unroll
    for (int t = 0; t < NTILE; ++t) {
        const short* xr = &Xs[(t * 16 + c) * PITCH + q * 8];
        short8 xa = *(const short8*)xr;
        short8 xb = *(const short8*)(xr + 32);

        floatx4 z = (floatx4)(0.0f);
        floatx4 acc[4];
        #pragma unroll
        for (int g = 0; g < 4; ++g) {
            acc[g] = __builtin_amdgcn_mfma_f32_16x16x32_bf16(xa, ya[g], z, 0, 0, 0);
            acc[g] = __builtin_amdgcn_mfma_f32_16x16x32_bf16(xb, yb[g], acc[g], 0, 0, 0);
        }

        // labels for this tile: m = t*16 + q*4 + j (broadcast within quad, shared by 4 groups)
        float4 lA = *(const float4*)&Lt[0 * CHUNK + t * 16 + q * 4];
        float4 lB = *(const float4*)&Lt[1 * CHUNK + t * 16 + q * 4];
        float4 lC = *(const float4*)&Lt[2 * CHUNK + t * 16 + q * 4];

        #pragma unroll
        for (int g = 0; g < 4; ++g) {
            float L0 = acc[g][0], L1 = acc[g][1], L2 = acc[g][2], L3 = acc[g][3];
            float tmax = fmaxf(fmaxf(L0, L1), fmaxf(L2, L3));
            float nm = fmaxf(ms[g], tmax);
            float sc = exp2f_(ms[g] - nm);
            float p0 = exp2f_(L0 - nm);
            float p1 = exp2f_(L1 - nm);
            float p2 = exp2f_(L2 - nm);
            float p3 = exp2f_(L3 - nm);
            sum[g] = sum[g] * sc + ((p0 + p1) + (p2 + p3));
            aA[g] = aA[g] * sc + ((p0 * lA.x + p1 * lA.y) + (p2 * lA.z + p3 * lA.w));
            aB[g] = aB[g] * sc + ((p0 * lB.x + p1 * lB.y) + (p2 * lB.z + p3 * lB.w));
            aC[g] = aC[g] * sc + ((p0 * lC.x + p1 * lC.y) + (p2 * lC.z + p3 * lC.w));
            ms[g] = nm;
        }
    }

    // butterfly merge across q (lane bits 4-5): 2 steps, 4 groups
    #pragma unroll
    for (int mask = 16; mask <= 32; mask <<= 1) {
        #pragma unroll
        for (int g = 0; g < 4; ++g) {
            float om = __shfl_xor(ms[g], mask, 64);
            float os = __shfl_xor(sum[g], mask, 64);
            float oA = __shfl_xor(aA[g], mask, 64);
            float oB = __shfl_xor(aB[g], mask, 64);
            float oC = __shfl_xor(aC[g], mask, 64);
            float nm = fmaxf(ms[g], om);
            float w1 = exp2f_(ms[g] - nm);
            float w2 = exp2f_(om - nm);
            sum[g] = sum[g] * w1 + os * w2;
            aA[g] = aA[g] * w1 + oA * w2;
            aB[g] = aB[g] * w1 + oB * w2;
            aC[g] = aC[g] * w1 + oC * w2;
            ms[g] = nm;
        }
    }

    if (q == 0) {
        size_t pbase = (size_t)(b * SPLIT + chunk) * 5 * NPIX;
        #pragma unroll
        for (int g = 0; g < 4; ++g) {
            int n = n_base + g * 16 + c;
            partials[pbase + 0 * NPIX + n] = ms[g];
            partials[pbase + 1 * NPIX + n] = sum[g];
            partials[pbase + 2 * NPIX + n] = aA[g];
            partials[pbase + 3 * NPIX + n] = aB[g];
            partials[pbase + 4 * NPIX + n] = aC[g];
        }
    }
}

// ---------------- Kernel 3: merge chunks, diff, L1+Huber, reduce ----------------
__global__ void loss_kernel(const float* __restrict__ partials,
                            const float* __restrict__ lab0ws,
                            float* __restrict__ out)
{
    int gid = blockIdx.x * blockDim.x + threadIdx.x;   // 0..8191
    int b = gid >> 12;
    int n = gid & (NPIX - 1);

    float M = -INFINITY;
    #pragma unroll
    for (int ch = 0; ch < SPLIT; ++ch)
        M = fmaxf(M, partials[((size_t)(b * SPLIT + ch) * 5 + 0) * NPIX + n]);
    float S = 0.0f, A0 = 0.0f, A1 = 0.0f, A2 = 0.0f;
    #pragma unroll
    for (int ch = 0; ch < SPLIT; ++ch) {
        size_t base = (size_t)(b * SPLIT + ch) * 5 * NPIX + n;
        float w = exp2f_(partials[base + 0 * NPIX] - M);
        S  += partials[base + 1 * NPIX] * w;
        A0 += partials[base + 2 * NPIX] * w;
        A1 += partials[base + 3 * NPIX] * w;
        A2 += partials[base + 4 * NPIX] * w;
    }
    float inv_s = 1.0f / S;
    float d0 = A0 * inv_s - lab0ws[(size_t)(b * 3 + 0) * NPIX + n];
    float d1 = A1 * inv_s - lab0ws[(size_t)(b * 3 + 1) * NPIX + n];
    float d2 = A2 * inv_s - lab0ws[(size_t)(b * 3 + 2) * NPIX + n];

    float val = 0.0f;
    #pragma unroll
    for (int cc = 0; cc < 3; ++cc) {
        float d = (cc == 0) ? d0 : (cc == 1) ? d1 : d2;
        float ad = fabsf(d);
        float hub = (ad < 1.0f) ? 0.5f * ad * ad : ad - 0.5f;
        val += ad + hub;
    }

    #pragma unroll
    for (int off = 32; off > 0; off >>= 1)
        val += __shfl_down(val, off);

    __shared__ float wsum[4];
    int lane = threadIdx.x & 63;
    int wave = threadIdx.x >> 6;
    if (lane == 0) wsum[wave] = val;
    __syncthreads();
    if (threadIdx.x == 0) {
        float s = wsum[0] + wsum[1] + wsum[2] + wsum[3];
        atomicAdd(out, s * (1.0f / 8192.0f));
    }
}

// ---------------- launcher ----------------
extern "C" void kernel_launch(void* const* d_in, const int* in_sizes, int n_in,
                              void* d_out, int out_size, void* d_ws, size_t ws_size,
                              hipStream_t stream) {
    const float* rgb0  = (const float*)d_in[0];
    const float* rgb1  = (const float*)d_in[1];
    const float* feat0 = (const float*)d_in[2];
    const float* feat1 = (const float*)d_in[3];
    float* out = (float*)d_out;
    float* ws  = (float*)d_ws;

    float* lab0 = ws;                         // 24576 floats
    float* lab1 = ws + 24576;                 // 24576 floats
    float* partials = ws + 49152;             // 2*32*5*4096 = 1310720 floats
    short* f0t = (short*)(ws + 49152 + 1310720);
    short* f1t = f0t + (size_t)BATCH * NPIX * FDIM;

    prep_kernel<<<320, 256, 0, stream>>>(rgb0, rgb1, feat0, feat1, lab0, lab1, f0t, f1t, out);

    int attn_grid = BATCH * SPLIT * (NPIX / BLKN);   // 1024 blocks x 256 threads
    attn_kernel<<<attn_grid, 256, 0, stream>>>(f0t, f1t, lab1, partials);

    loss_kernel<<<(BATCH * NPIX) / 256, 256, 0, stream>>>(partials, lab0, out);
}

// Round 11
// 82.743 us; speedup vs baseline: 1.0836x; 1.0836x over previous
//
#include <hip/hip_runtime.h>
#include <math.h>

#define NPIX   4096
#define FDIM   64
#define BATCH  2
#define SPLIT  16
#define CHUNK  (NPIX / SPLIT)      // 256
#define NTILE  (CHUNK / 16)        // 16 m-tiles of 16
#define BLKN   256                 // n-rows per block (8 waves x 32)
#define PITCH  72                  // shorts per LDS X row (64 + 8 pad)

typedef __attribute__((ext_vector_type(8))) short short8;
typedef __attribute__((ext_vector_type(4))) float floatx4;

__device__ __forceinline__ float exp2f_(float x) { return __builtin_amdgcn_exp2f(x); }

// round-to-nearest-even fp32 -> bf16
__device__ __forceinline__ short f2bf(float x) {
    union { float f; unsigned u; } c; c.f = x;
    unsigned r = (c.u + 0x7FFFu + ((c.u >> 16) & 1u)) >> 16;
    return (short)r;
}

// ---------------- LAB helpers ----------------
__device__ __forceinline__ float gamma_expand(float u) {
    return u > 0.04045f ? powf((u + 0.055f) * (1.0f / 1.055f), 2.4f)
                        : u * (1.0f / 12.92f);
}
__device__ __forceinline__ float lab_f(float t) {
    return t > 0.008856f ? cbrtf(t) : 7.787f * t + (16.0f / 116.0f);
}

// ---------------- Kernel 1: prep = feat transpose->bf16 (blocks 0..255) + LAB (blocks 256..319) ----
// f0t/f1t: [b][n][f] bf16; f0t pre-scaled by log2(e)/0.07 (logits in log2 space).
__global__ __launch_bounds__(256) void prep_kernel(
    const float* __restrict__ rgb0, const float* __restrict__ rgb1,
    const float* __restrict__ feat0, const float* __restrict__ feat1,
    float* __restrict__ lab0, float* __restrict__ lab1,
    short* __restrict__ f0t, short* __restrict__ f1t,
    float* __restrict__ out)
{
    int bid = blockIdx.x;
    int tid = threadIdx.x;

    if (bid < 256) {
        __shared__ short Tsm[64 * 72];
        int pair = bid >> 6;            // 0..3
        int tensor = pair >> 1;         // 0: f0, 1: f1
        int bb = pair & 1;
        int n0 = (bid & 63) * 64;
        const float* src = (tensor ? feat1 : feat0) + (size_t)bb * FDIM * NPIX;
        short* dst = (tensor ? f1t : f0t) + (size_t)bb * NPIX * FDIM;
        float scale = tensor ? 1.0f : (1.442695040888963f / 0.07f);

        int f = tid >> 2;
        int slot = tid & 3;
        #pragma unroll
        for (int i = 0; i < 4; ++i) {
            int col4 = slot * 4 + i;
            int noff = col4 * 4;
            float4 v = *(const float4*)&src[(size_t)f * NPIX + n0 + noff];
            Tsm[(noff + 0) * 72 + f] = f2bf(v.x * scale);
            Tsm[(noff + 1) * 72 + f] = f2bf(v.y * scale);
            Tsm[(noff + 2) * 72 + f] = f2bf(v.z * scale);
            Tsm[(noff + 3) * 72 + f] = f2bf(v.w * scale);
        }
        __syncthreads();
        #pragma unroll
        for (int i = 0; i < 2; ++i) {
            int idx = i * 256 + tid;
            int row = idx >> 3, ch = idx & 7;
            *(short8*)&dst[(size_t)(n0 + row) * FDIM + ch * 8] =
                *(const short8*)&Tsm[row * 72 + ch * 8];
        }
        return;
    }

    if (bid == 256 && tid == 0) out[0] = 0.0f;   // zero-init for loss atomicAdd

    // LAB branch
    int gid = (bid - 256) * 256 + tid;     // 0 .. 16383
    int img = gid / (BATCH * NPIX);
    int rem = gid - img * (BATCH * NPIX);
    int b = rem / NPIX;
    int n = rem - b * NPIX;
    const float* rgb = img ? rgb1 : rgb0;
    float* lab = img ? lab1 : lab0;

    size_t i0 = (size_t)(b * 3 + 0) * NPIX + n;
    size_t i1 = (size_t)(b * 3 + 1) * NPIX + n;
    size_t i2 = (size_t)(b * 3 + 2) * NPIX + n;

    float r = gamma_expand(rgb[i0] + 0.5f);
    float g = gamma_expand(rgb[i1] + 0.5f);
    float bl = gamma_expand(rgb[i2] + 0.5f);

    float X = (0.412453f * r + 0.357580f * g + 0.180423f * bl) * (1.0f / 0.95047f);
    float Y = (0.212671f * r + 0.715160f * g + 0.072169f * bl);
    float Z = (0.019334f * r + 0.119193f * g + 0.950227f * bl) * (1.0f / 1.08883f);

    float fx = lab_f(X), fy = lab_f(Y), fz = lab_f(Z);
    float L = 116.0f * fy - 16.0f;
    float a = 500.0f * (fx - fy);
    float bb2 = 200.0f * (fy - fz);

    lab[i0] = (L - 50.0f) * (1.0f / 100.0f);
    lab[i1] = a * (1.0f / 110.0f);
    lab[i2] = bb2 * (1.0f / 110.0f);
}

// ---------------- Kernel 2: MFMA attn — X chunk staged ONCE per block in LDS, 8 waves share ----------------
// mfma(X=f1 rows m, Y=f0 rows n): D[row=q*4+r <-> m][col=lane&15 <-> n]  (bench-verified R5-R10).
// 512-thread blocks (8 waves), grid 512 -> 2 blocks/CU, 4 waves/SIMD. One barrier total; main
// loop is ds_read_b128 + MFMA + softmax only (zero global loads). Pad-72 rows -> uniform banks.
// NOTE R10: SPLIT=32 + 4 groups/wave regressed (doubled partials traffic + merge work,
// halved per-block tile amortization). This SPLIT=16 / G=2 config is the measured optimum.
__global__ __launch_bounds__(512, 4) void attn_kernel(
    const short* __restrict__ f0t, const short* __restrict__ f1t,
    const float* __restrict__ lab1ws, float* __restrict__ partials)
{
    __shared__ short Xs[CHUNK * PITCH];    // 36 KB
    __shared__ float Lt[3 * CHUNK];        // 3 KB

    int bid = blockIdx.x;
    int rowblk = bid & 15;                 // 16 rowblocks of 256 n
    int chunk = (bid >> 4) & (SPLIT - 1);
    int b = bid >> 8;
    int tid = threadIdx.x;
    int wv = tid >> 6;                     // 0..7
    int l = tid & 63;
    int c = l & 15;
    int q = l >> 4;

    int n_base = rowblk * BLKN + wv * 32;  // this wave: rows n_base+c (g0), n_base+16+c (g1)
    int m_base = chunk * CHUNK;

    // stage labels for the m-chunk (3 x 256 floats)
    if (tid < 192) {
        int cc = tid >> 6;
        int m4 = tid & 63;
        *(float4*)&Lt[cc * CHUNK + m4 * 4] =
            *(const float4*)&lab1ws[(size_t)(b * 3 + cc) * NPIX + m_base + m4 * 4];
    }

    // stage X: 256 rows x 64 bf16 = 2048 chunks of 16B; straight copy, padded rows
    {
        const short8* src = (const short8*)(f1t + ((size_t)b * NPIX + m_base) * FDIM);
        #pragma unroll
        for (int i = 0; i < 4; ++i) {
            int g = i * 512 + tid;         // 0..2047
            int m = g >> 3, kc = g & 7;
            *(short8*)&Xs[m * PITCH + kc * 8] = src[g];
        }
    }

    // Y fragments (f0, n-rows), 2 groups, straight from global (one-time)
    short8 ya[2], yb[2];
    #pragma unroll
    for (int g = 0; g < 2; ++g) {
        const short8* yp = (const short8*)(f0t +
            ((size_t)b * NPIX + n_base + g * 16 + c) * FDIM + q * 8);
        ya[g] = yp[0];
        yb[g] = yp[4];
    }

    __syncthreads();

    float ms[2], sum[2], aA[2], aB[2], aC[2];
    #pragma unroll
    for (int g = 0; g < 2; ++g) {
        ms[g] = -INFINITY; sum[g] = 0.0f;
        aA[g] = 0.0f; aB[g] = 0.0f; aC[g] = 0.0f;
    }

    #pragma unroll
    for (int t = 0; t < NTILE; ++t) {
        const short* xr = &Xs[(t * 16 + c) * PITCH + q * 8];
        short8 xa = *(const short8*)xr;
        short8 xb = *(const short8*)(xr + 32);

        floatx4 z = (floatx4)(0.0f);
        floatx4 acc[2];
        #pragma unroll
        for (int g = 0; g < 2; ++g) {
            acc[g] = __builtin_amdgcn_mfma_f32_16x16x32_bf16(xa, ya[g], z, 0, 0, 0);
            acc[g] = __builtin_amdgcn_mfma_f32_16x16x32_bf16(xb, yb[g], acc[g], 0, 0, 0);
        }

        // labels for this tile: m = t*16 + q*4 + j (broadcast within quad)
        float4 lA = *(const float4*)&Lt[0 * CHUNK + t * 16 + q * 4];
        float4 lB = *(const float4*)&Lt[1 * CHUNK + t * 16 + q * 4];
        float4 lC = *(const float4*)&Lt[2 * CHUNK + t * 16 + q * 4];

        #pragma unroll
        for (int g = 0; g < 2; ++g) {
            float L0 = acc[g][0], L1 = acc[g][1], L2 = acc[g][2], L3 = acc[g][3];
            float tmax = fmaxf(fmaxf(L0, L1), fmaxf(L2, L3));
            float nm = fmaxf(ms[g], tmax);
            float sc = exp2f_(ms[g] - nm);
            float p0 = exp2f_(L0 - nm);
            float p1 = exp2f_(L1 - nm);
            float p2 = exp2f_(L2 - nm);
            float p3 = exp2f_(L3 - nm);
            sum[g] = sum[g] * sc + ((p0 + p1) + (p2 + p3));
            aA[g] = aA[g] * sc + ((p0 * lA.x + p1 * lA.y) + (p2 * lA.z + p3 * lA.w));
            aB[g] = aB[g] * sc + ((p0 * lB.x + p1 * lB.y) + (p2 * lB.z + p3 * lB.w));
            aC[g] = aC[g] * sc + ((p0 * lC.x + p1 * lC.y) + (p2 * lC.z + p3 * lC.w));
            ms[g] = nm;
        }
    }

    // butterfly merge across q (lane bits 4-5): 2 steps, 2 groups
    #pragma unroll
    for (int mask = 16; mask <= 32; mask <<= 1) {
        #pragma unroll
        for (int g = 0; g < 2; ++g) {
            float om = __shfl_xor(ms[g], mask, 64);
            float os = __shfl_xor(sum[g], mask, 64);
            float oA = __shfl_xor(aA[g], mask, 64);
            float oB = __shfl_xor(aB[g], mask, 64);
            float oC = __shfl_xor(aC[g], mask, 64);
            float nm = fmaxf(ms[g], om);
            float w1 = exp2f_(ms[g] - nm);
            float w2 = exp2f_(om - nm);
            sum[g] = sum[g] * w1 + os * w2;
            aA[g] = aA[g] * w1 + oA * w2;
            aB[g] = aB[g] * w1 + oB * w2;
            aC[g] = aC[g] * w1 + oC * w2;
            ms[g] = nm;
        }
    }

    if (q == 0) {
        size_t pbase = (size_t)(b * SPLIT + chunk) * 5 * NPIX;
        #pragma unroll
        for (int g = 0; g < 2; ++g) {
            int n = n_base + g * 16 + c;
            partials[pbase + 0 * NPIX + n] = ms[g];
            partials[pbase + 1 * NPIX + n] = sum[g];
            partials[pbase + 2 * NPIX + n] = aA[g];
            partials[pbase + 3 * NPIX + n] = aB[g];
            partials[pbase + 4 * NPIX + n] = aC[g];
        }
    }
}

// ---------------- Kernel 3: merge chunks, diff, L1+Huber, reduce ----------------
__global__ void loss_kernel(const float* __restrict__ partials,
                            const float* __restrict__ lab0ws,
                            float* __restrict__ out)
{
    int gid = blockIdx.x * blockDim.x + threadIdx.x;   // 0..8191
    int b = gid >> 12;
    int n = gid & (NPIX - 1);

    float M = -INFINITY;
    #pragma unroll
    for (int ch = 0; ch < SPLIT; ++ch)
        M = fmaxf(M, partials[((size_t)(b * SPLIT + ch) * 5 + 0) * NPIX + n]);
    float S = 0.0f, A0 = 0.0f, A1 = 0.0f, A2 = 0.0f;
    #pragma unroll
    for (int ch = 0; ch < SPLIT; ++ch) {
        size_t base = (size_t)(b * SPLIT + ch) * 5 * NPIX + n;
        float w = exp2f_(partials[base + 0 * NPIX] - M);
        S  += partials[base + 1 * NPIX] * w;
        A0 += partials[base + 2 * NPIX] * w;
        A1 += partials[base + 3 * NPIX] * w;
        A2 += partials[base + 4 * NPIX] * w;
    }
    float inv_s = 1.0f / S;
    float d0 = A0 * inv_s - lab0ws[(size_t)(b * 3 + 0) * NPIX + n];
    float d1 = A1 * inv_s - lab0ws[(size_t)(b * 3 + 1) * NPIX + n];
    float d2 = A2 * inv_s - lab0ws[(size_t)(b * 3 + 2) * NPIX + n];

    float val = 0.0f;
    #pragma unroll
    for (int cc = 0; cc < 3; ++cc) {
        float d = (cc == 0) ? d0 : (cc == 1) ? d1 : d2;
        float ad = fabsf(d);
        float hub = (ad < 1.0f) ? 0.5f * ad * ad : ad - 0.5f;
        val += ad + hub;
    }

    #pragma unroll
    for (int off = 32; off > 0; off >>= 1)
        val += __shfl_down(val, off);

    __shared__ float wsum[4];
    int lane = threadIdx.x & 63;
    int wave = threadIdx.x >> 6;
    if (lane == 0) wsum[wave] = val;
    __syncthreads();
    if (threadIdx.x == 0) {
        float s = wsum[0] + wsum[1] + wsum[2] + wsum[3];
        atomicAdd(out, s * (1.0f / 8192.0f));
    }
}

// ---------------- launcher ----------------
extern "C" void kernel_launch(void* const* d_in, const int* in_sizes, int n_in,
                              void* d_out, int out_size, void* d_ws, size_t ws_size,
                              hipStream_t stream) {
    const float* rgb0  = (const float*)d_in[0];
    const float* rgb1  = (const float*)d_in[1];
    const float* feat0 = (const float*)d_in[2];
    const float* feat1 = (const float*)d_in[3];
    float* out = (float*)d_out;
    float* ws  = (float*)d_ws;

    float* lab0 = ws;                         // 24576 floats
    float* lab1 = ws + 24576;                 // 24576 floats
    float* partials = ws + 49152;             // 2*16*5*4096 = 655360 floats
    short* f0t = (short*)(ws + 49152 + 655360);
    short* f1t = f0t + (size_t)BATCH * NPIX * FDIM;

    prep_kernel<<<320, 256, 0, stream>>>(rgb0, rgb1, feat0, feat1, lab0, lab1, f0t, f1t, out);

    int attn_grid = BATCH * SPLIT * (NPIX / BLKN);   // 512 blocks x 512 threads
    attn_kernel<<<attn_grid, 512, 0, stream>>>(f0t, f1t, lab1, partials);

    loss_kernel<<<(BATCH * NPIX) / 256, 256, 0, stream>>>(partials, lab0, out);
}